// Round 1
// 276.018 us; speedup vs baseline: 1.0387x; 1.0387x over previous
//
#include <hip/hip_runtime.h>
#include <math.h>

// ActionEmbedding: h = a[:,:3] @ pos_W + pos_b + sincos(euler(quat)) @ rot_W
//                      + rot_b + open_emb[idx];  out = LayerNorm(h) * g + b
// B = 65536 rows, H = 1024 cols, fp32.  Write floor: 268 MB -> ~43 us.
//
// h is rank-11: h[r] = sum_k c_k[r] * W_k over 11 basis vectors
//   (wp0..2, wr0..5, dopen, bb) with c_bb = 1.  So
//   mean = c.S/H,  E[h^2] = c^T G c / H,  G = W W^T (11x11).
// Kernel 1 (132 blocks) computes S and G into d_ws once per launch.
// Kernel 2 computes per-row mu/rstd from S,G analytically -> the row loop is
// pure FMA + coalesced float4 store: NO shuffles, NO in-loop barriers.
//
// R4 (this round): RPB 32->64 (full-wave setup, half the setups),
// plain cached stores (match fillBuffer's 6.36 TB/s write path, vs
// nontemporal), row loop manually unrolled 2x with hoisted LDS reads.

#define HDIM  1024
#define TPB   256
#define CPT   4    // HDIM / TPB columns per thread
#define RPB   64   // rows per block (== one full wave does setup)
#define NB    11   // basis vectors

typedef float v4f __attribute__((ext_vector_type(4)));

__device__ __forceinline__ float basis_val(
    int k, int c,
    const float* __restrict__ pos_W, const float* __restrict__ pos_b,
    const float* __restrict__ rot_W, const float* __restrict__ rot_b,
    const float* __restrict__ open_emb)
{
    if (k < 3)  return pos_W[k * HDIM + c];
    if (k < 9)  return rot_W[(k - 3) * HDIM + c];
    if (k == 9) return open_emb[HDIM + c] - open_emb[c];          // dopen
    return pos_b[c] + rot_b[c] + open_emb[c];                     // bb
}

// ws layout: [0..120] G (11x11 row-major), [121..131] S
__global__ __launch_bounds__(TPB) void gram_kernel(
    const float* __restrict__ pos_W, const float* __restrict__ pos_b,
    const float* __restrict__ rot_W, const float* __restrict__ rot_b,
    const float* __restrict__ open_emb, float* __restrict__ ws)
{
    __shared__ float s_part[4];
    const int b   = blockIdx.x;
    const int tid = threadIdx.x;
    float acc = 0.0f;
    if (b < NB * NB) {
        const int k = b / NB, l = b % NB;
        #pragma unroll
        for (int i = 0; i < HDIM / TPB; ++i) {
            const int c = tid + i * TPB;
            acc = fmaf(basis_val(k, c, pos_W, pos_b, rot_W, rot_b, open_emb),
                       basis_val(l, c, pos_W, pos_b, rot_W, rot_b, open_emb),
                       acc);
        }
    } else {
        const int k = b - NB * NB;
        #pragma unroll
        for (int i = 0; i < HDIM / TPB; ++i) {
            const int c = tid + i * TPB;
            acc += basis_val(k, c, pos_W, pos_b, rot_W, rot_b, open_emb);
        }
    }
    #pragma unroll
    for (int off = 32; off > 0; off >>= 1)
        acc += __shfl_xor(acc, off, 64);
    if ((tid & 63) == 0) s_part[tid >> 6] = acc;
    __syncthreads();
    if (tid == 0)
        ws[b] = (s_part[0] + s_part[1]) + (s_part[2] + s_part[3]);
}

__global__ __launch_bounds__(TPB) void action_embed_kernel(
    const float* __restrict__ actions,
    const float* __restrict__ pos_W, const float* __restrict__ pos_b,
    const float* __restrict__ rot_W, const float* __restrict__ rot_b,
    const float* __restrict__ open_emb,
    const float* __restrict__ ln_g, const float* __restrict__ ln_b,
    const float* __restrict__ ws,
    float* __restrict__ out, int B)
{
    // per-row: c0'..c9' (rstd-scaled coefs), rstd, mu*rstd  -- 12 floats
    __shared__ float s_coef[RPB][12];

    const int tid  = threadIdx.x;
    const int col  = tid * CPT;
    const int row0 = blockIdx.x * RPB;

    // ---- weights for this thread's 4 columns -> registers (once per block) ----
    const float4 wp0 = *(const float4*)(pos_W + 0 * HDIM + col);
    const float4 wp1 = *(const float4*)(pos_W + 1 * HDIM + col);
    const float4 wp2 = *(const float4*)(pos_W + 2 * HDIM + col);
    const float4 wr0 = *(const float4*)(rot_W + 0 * HDIM + col);
    const float4 wr1 = *(const float4*)(rot_W + 1 * HDIM + col);
    const float4 wr2 = *(const float4*)(rot_W + 2 * HDIM + col);
    const float4 wr3 = *(const float4*)(rot_W + 3 * HDIM + col);
    const float4 wr4 = *(const float4*)(rot_W + 4 * HDIM + col);
    const float4 wr5 = *(const float4*)(rot_W + 5 * HDIM + col);
    float4 bb, dopen;
    {
        const float4 pb = *(const float4*)(pos_b + col);
        const float4 rb = *(const float4*)(rot_b + col);
        const float4 o0 = *(const float4*)(open_emb + 0 * HDIM + col);
        const float4 o1 = *(const float4*)(open_emb + 1 * HDIM + col);
        bb    = make_float4(pb.x + rb.x + o0.x, pb.y + rb.y + o0.y,
                            pb.z + rb.z + o0.z, pb.w + rb.w + o0.w);
        dopen = make_float4(o1.x - o0.x, o1.y - o0.y, o1.z - o0.z, o1.w - o0.w);
    }
    const float4 g  = *(const float4*)(ln_g + col);
    const float4 bt = *(const float4*)(ln_b + col);

    // ---- per-row coefficients + analytic LN moments (wave 0, 64 rows) ----
    if (tid < RPB) {
        const int r = row0 + tid;
        if (r < B) {
            const float4 a0 = *(const float4*)(actions + (size_t)r * 8);
            const float4 a1 = *(const float4*)(actions + (size_t)r * 8 + 4);
            float qx = a0.w, qy = a1.x, qz = a1.y, qw = a1.z;
            const float n = 1.0f / sqrtf(qx * qx + qy * qy + qz * qz + qw * qw);
            qx *= n; qy *= n; qz *= n; qw *= n;
            // sin/cos(atan2(a,b)) = a/hyp, b/hyp
            const float sr_n = 2.0f * (qw * qx + qy * qz);
            const float cr_n = 1.0f - 2.0f * (qx * qx + qy * qy);
            float sr, cr;
            {
                const float r2 = sr_n * sr_n + cr_n * cr_n;
                if (r2 < 1e-37f) { sr = 0.0f; cr = 1.0f; }
                else { const float ri = 1.0f / sqrtf(r2); sr = sr_n * ri; cr = cr_n * ri; }
            }
            // sin/cos(asin(t)) = t, sqrt(1-t^2)
            float sp = 2.0f * (qw * qy - qz * qx);
            sp = fminf(1.0f, fmaxf(-1.0f, sp));
            const float cp = sqrtf(fmaxf(0.0f, 1.0f - sp * sp));
            const float sy_n = 2.0f * (qw * qz + qx * qy);
            const float cy_n = 1.0f - 2.0f * (qy * qy + qz * qz);
            float sy, cy;
            {
                const float r2 = sy_n * sy_n + cy_n * cy_n;
                if (r2 < 1e-37f) { sy = 0.0f; cy = 1.0f; }
                else { const float ri = 1.0f / sqrtf(r2); sy = sy_n * ri; cy = cy_n * ri; }
            }
            int idx = (int)a1.w;
            idx = idx < 0 ? 0 : (idx > 1 ? 1 : idx);

            float c[NB];
            c[0] = a0.x; c[1] = a0.y; c[2] = a0.z;
            c[3] = sr;   c[4] = sp;   c[5] = sy;
            c[6] = cr;   c[7] = cp;   c[8] = cy;
            c[9] = (float)idx;
            c[10] = 1.0f;   // bb coefficient

            // mu = (c . S) / H
            float mdot = 0.0f;
            #pragma unroll
            for (int k = 0; k < NB; ++k)
                mdot = fmaf(c[k], ws[NB * NB + k], mdot);
            const float mu = mdot * (1.0f / HDIM);
            // E[h^2] = c^T G c / H
            float q = 0.0f;
            #pragma unroll
            for (int k = 0; k < NB; ++k) {
                float t = 0.0f;
                #pragma unroll
                for (int l = 0; l < NB; ++l)
                    t = fmaf(ws[k * NB + l], c[l], t);
                q = fmaf(c[k], t, q);
            }
            float var = fmaf(q, 1.0f / HDIM, -mu * mu);
            var = fmaxf(var, 0.0f);
            const float rstd = 1.0f / sqrtf(var + 1e-12f);

            #pragma unroll
            for (int k = 0; k < 10; ++k)
                s_coef[tid][k] = c[k] * rstd;
            s_coef[tid][10] = rstd;        // scales bb
            s_coef[tid][11] = mu * rstd;   // subtracted
        }
    }
    __syncthreads();

#define ROWCOMP(O, K0, K1, K2, f)                                           \
        {                                                                   \
            float hh = fmaf(K2.z, bb.f, -K2.w);                             \
            hh = fmaf(K0.x, wp0.f, hh);                                     \
            hh = fmaf(K0.y, wp1.f, hh);                                     \
            hh = fmaf(K0.z, wp2.f, hh);                                     \
            hh = fmaf(K0.w, wr0.f, hh);                                     \
            hh = fmaf(K1.x, wr1.f, hh);                                     \
            hh = fmaf(K1.y, wr2.f, hh);                                     \
            hh = fmaf(K1.z, wr3.f, hh);                                     \
            hh = fmaf(K1.w, wr4.f, hh);                                     \
            hh = fmaf(K2.x, wr5.f, hh);                                     \
            hh = fmaf(K2.y, dopen.f, hh);                                   \
            O.f = fmaf(hh, g.f, bt.f);                                      \
        }
#define ROW_ALL(O, K0, K1, K2)                                              \
        ROWCOMP(O, K0, K1, K2, x) ROWCOMP(O, K0, K1, K2, y)                 \
        ROWCOMP(O, K0, K1, K2, z) ROWCOMP(O, K0, K1, K2, w)

    float* orow = out + (size_t)row0 * HDIM + col;

    if (row0 + RPB <= B) {
        // full block: 64 rows, unrolled 2x, plain cached stores
        for (int rr = 0; rr < RPB; rr += 2) {
            const float4 a0 = *(const float4*)&s_coef[rr][0];
            const float4 a1 = *(const float4*)&s_coef[rr][4];
            const float4 a2 = *(const float4*)&s_coef[rr][8];
            const float4 b0 = *(const float4*)&s_coef[rr + 1][0];
            const float4 b1 = *(const float4*)&s_coef[rr + 1][4];
            const float4 b2 = *(const float4*)&s_coef[rr + 1][8];
            v4f oa, ob;
            ROW_ALL(oa, a0, a1, a2);
            ROW_ALL(ob, b0, b1, b2);
            *(v4f*)orow = oa;
            *(v4f*)(orow + HDIM) = ob;
            orow += 2 * HDIM;
        }
    } else {
        const int nrows = B - row0;
        for (int rr = 0; rr < nrows; ++rr) {
            const float4 a0 = *(const float4*)&s_coef[rr][0];
            const float4 a1 = *(const float4*)&s_coef[rr][4];
            const float4 a2 = *(const float4*)&s_coef[rr][8];
            v4f oa;
            ROW_ALL(oa, a0, a1, a2);
            *(v4f*)orow = oa;
            orow += HDIM;
        }
    }
#undef ROW_ALL
#undef ROWCOMP
}

extern "C" void kernel_launch(void* const* d_in, const int* in_sizes, int n_in,
                              void* d_out, int out_size, void* d_ws, size_t ws_size,
                              hipStream_t stream) {
    const float* actions  = (const float*)d_in[0];
    const float* pos_W    = (const float*)d_in[1];
    const float* pos_b    = (const float*)d_in[2];
    const float* rot_W    = (const float*)d_in[3];
    const float* rot_b    = (const float*)d_in[4];
    const float* open_emb = (const float*)d_in[5];
    const float* ln_g     = (const float*)d_in[6];
    const float* ln_b     = (const float*)d_in[7];
    float* out = (float*)d_out;
    float* ws  = (float*)d_ws;

    const int B = in_sizes[0] / 8;
    hipLaunchKernelGGL(gram_kernel, dim3(NB * NB + NB), dim3(TPB), 0, stream,
                       pos_W, pos_b, rot_W, rot_b, open_emb, ws);
    const int grid = (B + RPB - 1) / RPB;
    hipLaunchKernelGGL(action_embed_kernel, dim3(grid), dim3(TPB), 0, stream,
                       actions, pos_W, pos_b, rot_W, rot_b, open_emb,
                       ln_g, ln_b, ws, out, B);
}